// Round 3
// baseline (26.834 us; speedup 1.0000x reference)
//
#include <hip/hip_runtime.h>
#include <cmath>

// FilterDelayNetwork: delay(1499) -> 1st-order IIR (pole p≈0.0194) -> tonal FIR.
// Collapsed to an 8-tap FIR since p^8 ~ 2e-14 (far below fp32 precision):
//   z[n] = sum_k h[k] * input[n - 1499 - k]
//   h[0] = b0/(1-beta); h[k] = h[0]*(p-beta)*p^(k-1)

#define NTAPS   8
#define DELAY   1499
#define WIN_OFF 1508   // (DELAY + NTAPS - 1) = 1506, rounded up to multiple of 4

struct Taps { float h[NTAPS]; };

__global__ __launch_bounds__(256)
void fdn_fir_kernel(const float* __restrict__ x, float* __restrict__ out,
                    const int n, const Taps taps)
{
    const long long t  = (long long)blockIdx.x * blockDim.x + threadIdx.x;
    const long long n0 = 4 * t;                 // first of 4 output indices
    if (n0 >= n) return;

    const long long base = n0 - WIN_OFF;        // 16B-aligned input-window start
    float v[16];

    if (base >= 0 && n0 + 4 <= n) {
        // Fast path: 4 aligned float4 loads covering x[base .. base+15].
        const float4* p4 = reinterpret_cast<const float4*>(x + base);
        float4 a = p4[0], b = p4[1], c = p4[2], d = p4[3];
        v[0]=a.x;  v[1]=a.y;  v[2]=a.z;  v[3]=a.w;
        v[4]=b.x;  v[5]=b.y;  v[6]=b.z;  v[7]=b.w;
        v[8]=c.x;  v[9]=c.y;  v[10]=c.z; v[11]=c.w;
        v[12]=d.x; v[13]=d.y; v[14]=d.z; v[15]=d.w;

        float o[4];
        #pragma unroll
        for (int j = 0; j < 4; ++j) {
            float acc = 0.0f;
            #pragma unroll
            for (int k = 0; k < NTAPS; ++k)
                acc = fmaf(taps.h[k], v[9 + j - k], acc);   // x[n0+j-1499-k]
            o[j] = acc;
        }
        *reinterpret_cast<float4*>(out + n0) = make_float4(o[0], o[1], o[2], o[3]);
    } else {
        // Slow path: head (implicit zero-pad of the delay line) / tail guard.
        #pragma unroll
        for (int i = 0; i < 16; ++i) {
            long long idx = base + i;
            v[i] = (idx >= 0 && idx < n) ? x[idx] : 0.0f;
        }
        for (int j = 0; j < 4; ++j) {
            long long nn = n0 + j;
            if (nn >= n) break;
            float acc = 0.0f;
            #pragma unroll
            for (int k = 0; k < NTAPS; ++k)
                acc = fmaf(taps.h[k], v[9 + j - k], acc);
            out[nn] = acc;
        }
    }
}

extern "C" void kernel_launch(void* const* d_in, const int* in_sizes, int n_in,
                              void* d_out, int out_size, void* d_ws, size_t ws_size,
                              hipStream_t stream)
{
    const float* x   = (const float*)d_in[0];
    float*       out = (float*)d_out;
    const int n = in_sizes[0];   // == out_size (2^24)

    // Module constants from the reference (host-side double math, exact).
    const double dd    = 1499.0;                 // DELAYS[0]
    const double t60   = 2.0;
    const double alpha = 0.7;
    const double fs    = 48000.0;

    const double g    = pow(10.0, -3.0 * dd / fs / t60);
    const double p    = log10(10.0 / 4.0) * (1.0 - 1.0 / (alpha * alpha)) * log10(g);
    const double b0   = g * (1.0 - p);
    const double beta = (1.0 - alpha) / (1.0 + alpha);
    const double c    = b0 / (1.0 - beta);

    Taps taps;
    taps.h[0] = (float)c;
    double pk = 1.0;
    for (int k = 1; k < NTAPS; ++k) {
        taps.h[k] = (float)(c * (p - beta) * pk);
        pk *= p;
    }

    const int nThreads = (n + 3) / 4;
    const int block = 256;
    const int grid  = (nThreads + block - 1) / block;
    hipLaunchKernelGGL(fdn_fir_kernel, dim3(grid), dim3(block), 0, stream,
                       x, out, n, taps);
}